// Round 10
// baseline (1171.025 us; speedup 1.0000x reference)
//
#include <hip/hip_runtime.h>

// Neural-ODE RK4 over MLP 12->300->100->50->12, B=1024, T=100.
// 256 blocks x 512 threads (8 waves), 4 batch elements per block, 1 block/CU.
// R10 = R9 + amdgpu_waves_per_eu(1,2): the allocator's default 128-VGPR cap
// (observed pinned-at-128 + scratch traffic in R7/R8/R9) is lifted to 256,
// which our real occupancy (2 waves/SIMD) supports for free. No structural
// change: h1T[k][e] transpose, packed v_pk_fma_f32 L2 (W2 in 76 regs),
// wave-local reduce+L3 tail, 4 barriers/eval.

typedef float v2f __attribute__((ext_vector_type(2)));
typedef float v4f __attribute__((ext_vector_type(4)));

constexpr int TT = 100;
constexpr int D  = 12;
constexpr int H1 = 300;
constexpr int H2 = 100;
constexpr int H3 = 50;
constexpr float NEG = 0.01f;

__device__ __forceinline__ float lrelu(float x) { return fmaxf(x, NEG * x); }
__device__ __forceinline__ v2f lo2(v4f v) { return __builtin_shufflevector(v, v, 0, 1); }
__device__ __forceinline__ v2f hi2(v4f v) { return __builtin_shufflevector(v, v, 2, 3); }
__device__ __forceinline__ v2f pkfma(v2f a, v2f b, v2f c) {
#if __has_builtin(__builtin_elementwise_fma)
    return __builtin_elementwise_fma(a, b, c);
#else
    return a * b + c;
#endif
}

__global__ __launch_bounds__(512)
__attribute__((amdgpu_waves_per_eu(1, 2)))
void node_rk4_kernel(const float* __restrict__ y0, const float* __restrict__ t,
                     const float* __restrict__ W1, const float* __restrict__ b1,
                     const float* __restrict__ W2, const float* __restrict__ b2,
                     const float* __restrict__ W3, const float* __restrict__ b3,
                     const float* __restrict__ W4, const float* __restrict__ b4,
                     float* __restrict__ out)
{
    // LDS ~ 59 KB
    __shared__ __align__(16) float sW1 [D * H1];    // [k][j] lane-contiguous
    __shared__ __align__(16) float sW3c[25 * 200];  // [c][j][4k] chunked W3
    __shared__ __align__(16) float sW4 [52 * 12];   // [k][j], rows 50,51 zero
    __shared__ __align__(16) float h1T [304 * 4];   // [k][e], k=300..303 zero
    __shared__ __align__(16) float pL2 [32 * 104];  // [(w*4+e)][104]
    __shared__ __align__(16) float h2e [4 * 104];   // [e][104]
    __shared__ __align__(16) float h3e [4 * 52];    // [e][52], 50,51 zero
    __shared__ __align__(16) float sx  [48];
    __shared__ __align__(16) float sxe [48];
    __shared__ __align__(16) float sks [48];
    __shared__ float st [100];

    const int tid = threadIdx.x;
    const int l   = tid & 63;
    const int w   = tid >> 6;            // wave 0..7 = L2 k-eighth
    const bool l2act = (l < 50);

    // ---- L1 bias only in reg (weights come from LDS each eval) ----
    const bool l1act = (tid < H1);
    const float rb1 = l1act ? b1[tid] : 0.0f;

    // ---- W2 in regs: wave w owns k = w*38 .. w*38+37; lane l owns cols l, l+50 ----
    float w2a[38], w2b[38];
#pragma unroll
    for (int i = 0; i < 38; ++i) {
        const int k = w * 38 + i;
        float va = 0.0f, vb = 0.0f;
        if (l2act && k < H1) { va = W2[k * H2 + l]; vb = W2[k * H2 + l + 50]; }
        w2a[i] = va; w2b[i] = vb;
    }

    // ---- tail-wave constants (waves 0-3, lanes<50) ----
    float rb2a = 0.f, rb2b = 0.f, rb3 = 0.f;
    if (w < 4 && l2act) { rb2a = b2[l]; rb2b = b2[l + 50]; rb3 = b3[l]; }

    // ---- L4 lane mapping (waves 4-6, 192 threads) ----
    const int u4 = tid - 256;
    const bool l4act = (u4 >= 0 && u4 < 192);
    int e4 = 0, j4 = 0, kq4 = 0;
    float b4v = 0.0f;
    if (l4act) {
        e4 = u4 / 48; const int r = u4 - e4 * 48; j4 = r >> 2; kq4 = r & 3;
        b4v = b4[j4];
    }

    // ---- one-time LDS staging ----
    for (int i = tid; i < D * H1; i += 512) sW1[i] = W1[i];          // [k][j]
    for (int i = tid; i < H2 * H3; i += 512) {      // W3 [k=100][j=50] -> chunked
        const int k = i / H3, j = i - k * H3;
        sW3c[(k >> 2) * 200 + j * 4 + (k & 3)] = W3[i];
    }
    for (int i = tid; i < 52 * 12; i += 512) sW4[i] = (i < H3 * D) ? W4[i] : 0.0f;
    if (tid < TT) st[tid] = t[tid];                 // t row 0 (uniform over batch)
    if (tid >= 104 && tid < 120) h1T[300 * 4 + (tid - 104)] = 0.0f;  // k=300..303
    if (tid >= 120 && tid < 128) {                  // h3e pads
        const int u = tid - 120;
        h3e[(u >> 1) * 52 + 50 + (u & 1)] = 0.0f;
    }
    if (tid < 48) {                                 // x0 = y0[:,0,:]; out[:,0,:]
        const int e = tid / 12, j = tid - e * 12;
        const int g = (blockIdx.x * 4 + e) * (TT * D) + j;
        const float v = y0[g];
        sx[tid] = v;
        out[g]  = v;
    }
    __syncthreads();

    for (int s = 0; s < TT - 1; ++s) {
#pragma unroll 1
        for (int ev = 0; ev < 4; ++ev) {
            const float* xin = ev ? sxe : sx;

            // ===== L1: 12 -> 300, col = tid, W1 from LDS, writes h1T[j][0..3] =====
            if (l1act) {
                float wv[12];
#pragma unroll
                for (int k = 0; k < 12; ++k) wv[k] = sW1[k * H1 + tid];
                v4f r;
#pragma unroll
                for (int e = 0; e < 4; ++e) {
                    const v4f x0 = *(const v4f*)(xin + e * 12);
                    const v4f x1 = *(const v4f*)(xin + e * 12 + 4);
                    const v4f x2 = *(const v4f*)(xin + e * 12 + 8);
                    float a = rb1;
                    a = fmaf(x0.x, wv[0], a);  a = fmaf(x0.y, wv[1], a);
                    a = fmaf(x0.z, wv[2], a);  a = fmaf(x0.w, wv[3], a);
                    a = fmaf(x1.x, wv[4], a);  a = fmaf(x1.y, wv[5], a);
                    a = fmaf(x1.z, wv[6], a);  a = fmaf(x1.w, wv[7], a);
                    a = fmaf(x2.x, wv[8], a);  a = fmaf(x2.y, wv[9], a);
                    a = fmaf(x2.z, wv[10], a); a = fmaf(x2.w, wv[11], a);
                    r[e] = lrelu(a);
                }
                *(v4f*)(h1T + tid * 4) = r;
            }
            __syncthreads();                        // A: h1T ready

            // ===== L2: 300 -> 100, reg weights, 1 b128 broadcast per k, packed =====
            {
                v2f a01A = {0,0}, a23A = {0,0}, a01B = {0,0}, a23B = {0,0};
                const float* hb = h1T + w * (38 * 4);
#pragma unroll
                for (int i = 0; i < 38; ++i) {
                    const v4f hv = *(const v4f*)(hb + i * 4);   // elems 0..3 at k
                    const v2f wA = {w2a[i], w2a[i]};
                    const v2f wB = {w2b[i], w2b[i]};
                    a01A = pkfma(lo2(hv), wA, a01A);
                    a23A = pkfma(hi2(hv), wA, a23A);
                    a01B = pkfma(lo2(hv), wB, a01B);
                    a23B = pkfma(hi2(hv), wB, a23B);
                }
                if (l2act) {
                    pL2[(w * 4 + 0) * 104 + l]      = a01A.x;
                    pL2[(w * 4 + 1) * 104 + l]      = a01A.y;
                    pL2[(w * 4 + 2) * 104 + l]      = a23A.x;
                    pL2[(w * 4 + 3) * 104 + l]      = a23A.y;
                    pL2[(w * 4 + 0) * 104 + l + 50] = a01B.x;
                    pL2[(w * 4 + 1) * 104 + l + 50] = a01B.y;
                    pL2[(w * 4 + 2) * 104 + l + 50] = a23B.x;
                    pL2[(w * 4 + 3) * 104 + l + 50] = a23B.y;
                }
            }
            __syncthreads();                        // B: pL2 ready

            // ===== wave-local tail: wave e<4 = elem e: reduce + L3, no barrier =====
            if (w < 4 && l2act) {
                const int e = w;
                // reduce 8 partials -> h2e[e][*]
                float va = rb2a, vb = rb2b;
#pragma unroll
                for (int q = 0; q < 8; ++q) {
                    va += pL2[(q * 4 + e) * 104 + l];
                    vb += pL2[(q * 4 + e) * 104 + l + 50];
                }
                h2e[e * 104 + l]      = lrelu(va);
                h2e[e * 104 + l + 50] = lrelu(vb);
                // in-wave LDS write->read (compiler emits lgkmcnt wait)
                v2f acc = {0, 0};
                const float* hb2 = h2e + e * 104;
                const float* wb  = sW3c + l * 4;
#pragma unroll
                for (int c = 0; c < 25; ++c) {
                    const v4f wv = *(const v4f*)(wb + c * 200);
                    const v4f hv = *(const v4f*)(hb2 + c * 4);
                    acc = pkfma(lo2(hv), lo2(wv), acc);
                    acc = pkfma(hi2(hv), hi2(wv), acc);
                }
                h3e[e * 52 + l] = lrelu(acc.x + acc.y + rb3);
            }
            __syncthreads();                        // D: h3 ready

            // ===== L4: 50 -> 12, waves 4-6, shfl reduce, fused RK4 =====
            if (l4act) {
                const int kb = kq4 * 13;
                float a = 0.0f;
                const float* hb3 = h3e + e4 * 52 + kb;
#pragma unroll
                for (int i = 0; i < 13; ++i)        // k<=51: pads are zero
                    a = fmaf(hb3[i], sW4[(kb + i) * 12 + j4], a);
                a += __shfl_xor(a, 1);
                a += __shfl_xor(a, 2);
                if (kq4 == 0) {
                    a += b4v;
                    const float dt = st[s + 1] - st[s];
                    const int bi = e4 * 12 + j4;
                    const float xc = sx[bi];
                    if (ev == 0)      { sks[bi] = a;        sxe[bi] = xc + 0.5f * dt * a; }
                    else if (ev == 1) { sks[bi] += 2.f * a; sxe[bi] = xc + 0.5f * dt * a; }
                    else if (ev == 2) { sks[bi] += 2.f * a; sxe[bi] = xc + dt * a; }
                    else {
                        const float xn = xc + dt * (1.0f / 6.0f) * (sks[bi] + a);
                        sx[bi] = xn;
                        out[(blockIdx.x * 4 + e4) * (TT * D) + (s + 1) * D + j4] = xn;
                    }
                }
            }
            __syncthreads();                        // E: state ready
        }
    }
}

extern "C" void kernel_launch(void* const* d_in, const int* in_sizes, int n_in,
                              void* d_out, int out_size, void* d_ws, size_t ws_size,
                              hipStream_t stream) {
    const float* y0 = (const float*)d_in[0];
    const float* t  = (const float*)d_in[1];
    const float* W1 = (const float*)d_in[2];
    const float* b1 = (const float*)d_in[3];
    const float* W2 = (const float*)d_in[4];
    const float* b2 = (const float*)d_in[5];
    const float* W3 = (const float*)d_in[6];
    const float* b3 = (const float*)d_in[7];
    const float* W4 = (const float*)d_in[8];
    const float* b4 = (const float*)d_in[9];
    float* out = (float*)d_out;

    node_rk4_kernel<<<256, 512, 0, stream>>>(y0, t, W1, b1, W2, b2, W3, b3, W4, b4, out);
}